// Round 15
// baseline (8773.537 us; speedup 1.0000x reference)
//
#include <hip/hip_runtime.h>
#include <math.h>

// NER BiLSTM-CRF on MI355X — fan-in-8 per-wave-dataflow persistent recurrence.
// fp32 throughout (Viterbi argmax flips are fatal: tags threshold 4.82, range 0..8).
//
// 256 blocks of 256 threads, 1/CU (LDS padded >80KB -> guaranteed 1 block/CU).
// Groups: g = bid&31 (d = g>>4, bg = g&15 -> 4 batches), ug = bid>>5 -> 32 units.
// Both Wih and Whh slices live in VGPRs (2 rows x 64k x 2 matrices = 256 VGPR).
// Wave ks owns K-window [ks*64, ks*64+64) -> needs h only from producers 2ks,2ks+1:
//   per-wave poll (one int4 of tags) + per-wave fill (one dwordx4 / lane, 16B)
//   -> NO block-level SYNC_A. Single __syncthreads per step (parts+emb handoff),
//   parts double-buffered by parity (waves race ahead; read(s) vs write(s+1)).
// Protocol per r7 (proven): all exchange sc0 sc1; vmcnt(0) INSIDE each asm block;
// "=&v" early-clobber; release = coalesced h stores -> wave vmcnt(0) -> wave tag.
// WAR chain: Z stores buf[par] at s+1 only after Z's 4 waves polled all 8 tags >= s+1,
// incl. mine, published after my SYNC_B(s) (my h2 reads of buf[par] are done). Safe.
//
// ws: h_hist [64 b][512 l][512 h] f32  67,108,864 @ 0
//     h2     [32 g][2 par][256 u][4 bb] f32  262,144 @ 67,108,864
//     tags   [32 g][8 ug][2 w] i32             2,048 @ 67,371,008
//     em     [512][64][9] f32              1,179,648 @ 67,373,056
//     last_tag [64] i32                          256 @ 68,552,704
//     hist   [64][512][9] u8                 294,912 @ 68,552,960
//     total 68,847,872 B (< 68,850,944 proven available in r7)

#define Bv 64
#define Lv 512

__device__ __forceinline__ float sigmoidf_(float x) { return 1.0f / (1.0f + expf(-x)); }

extern __shared__ char dyn_pad[];   // launch-time 56000B pad forces 1 block/CU

__global__ __launch_bounds__(256, 1) void lstm_persist(
    const int* __restrict__ x, const float* __restrict__ embed,
    const float* __restrict__ Wih_f, const float* __restrict__ Whh_f, const float* __restrict__ bf,
    const float* __restrict__ Wih_b, const float* __restrict__ Whh_b, const float* __restrict__ bb_,
    float* __restrict__ h2, int* __restrict__ tags, float* __restrict__ h_hist)
{
    const int bid = blockIdx.x;
    const int g  = bid & 31;          // sync group (8 blocks)
    const int d  = g >> 4;            // direction
    const int bg = g & 15;            // batch group (4 batches)
    const int ug = bid >> 5;          // unit group (32 units)
    const int tid = threadIdx.x;
    const int lane = tid & 63;
    const int ks = tid >> 6;          // wave = K-window [ks*64, ks*64+64)
    const int u0 = ug * 32;
    const int b0 = bg * 4;

    const float* Wih  = d ? Wih_b : Wih_f;
    const float* Whh  = d ? Whh_b : Whh_f;
    const float* bias = d ? bb_   : bf;

    __shared__ float emb_lds[2][4][260];     // [par][bb][k]
    __shared__ float h_lds[4][260];          // [bb][u] — wave-private column slices
    __shared__ float parts[2][4][128][5];    // [par][ks][local gate row][bb]
    __shared__ float bias_lds[128];

    // ---- BOTH weight slices to VGPRs: local rows {lane, lane+64}, K-window 64 ----
    // local row lr -> global gate row (lr>>5)*256 + u0 + (lr&31)
    float4 wih[2][16], whh[2][16];
    #pragma unroll
    for (int i = 0; i < 2; ++i) {
        const int lr = lane + 64 * i;
        const size_t grow = (size_t)((lr >> 5) * 256 + u0 + (lr & 31));
        const float* wi = Wih + grow * 256 + ks * 64;
        const float* wh = Whh + grow * 256 + ks * 64;
        #pragma unroll
        for (int m = 0; m < 16; ++m) {
            wih[i][m] = *reinterpret_cast<const float4*>(wi + 4 * m);
            whh[i][m] = *reinterpret_cast<const float4*>(wh + 4 * m);
        }
    }
    if (tid < 128)
        bias_lds[tid] = bias[(tid >> 5) * 256 + u0 + (tid & 31)];

    // zero h_lds (h(0) = 0), stage emb for step 0
    for (int i = tid; i < 4 * 260; i += 256) h_lds[i / 260][i % 260] = 0.f;
    {
        const int b = tid >> 6, cseg = tid & 63;
        const int t0 = d ? (Lv - 1) : 0;
        const int xv = x[(b0 + b) * Lv + t0];
        *reinterpret_cast<float4*>(&emb_lds[0][b][cseg * 4]) =
            *reinterpret_cast<const float4*>(embed + (size_t)xv * 256 + cseg * 4);
    }
    __syncthreads();

    float creg = 0.f;   // cell state for tid<128: unit u0+(tid>>2), batch b0+(tid&3)

    for (int tt = 0; tt < Lv; ++tt) {
        const int par = tt & 1;

        // ---- 1. gx dot: wih(regs) . emb_lds[par] (K-window ks*64..+64) ----
        float acc[2][4];
        #pragma unroll
        for (int i = 0; i < 2; ++i)
            #pragma unroll
            for (int u = 0; u < 4; ++u) acc[i][u] = 0.f;
        #pragma unroll
        for (int m = 0; m < 16; ++m) {
            float4 ev[4];
            #pragma unroll
            for (int u = 0; u < 4; ++u)
                ev[u] = *reinterpret_cast<const float4*>(&emb_lds[par][u][ks * 64 + 4 * m]);
            #pragma unroll
            for (int i = 0; i < 2; ++i) {
                const float4 wv = wih[i][m];
                #pragma unroll
                for (int u = 0; u < 4; ++u)
                    acc[i][u] += wv.x * ev[u].x + wv.y * ev[u].y + wv.z * ev[u].z + wv.w * ev[u].w;
            }
        }

        // ---- 2. stage emb for tt+1 into emb_lds[par^1] ----
        if (tt + 1 < Lv) {
            const int b = tid >> 6, cseg = tid & 63;
            const int t1 = d ? (Lv - 2 - tt) : (tt + 1);
            const int xv = x[(b0 + b) * Lv + t1];
            *reinterpret_cast<float4*>(&emb_lds[par ^ 1][b][cseg * 4]) =
                *reinterpret_cast<const float4*>(embed + (size_t)xv * 256 + cseg * 4);
        }

        // ---- 3. per-wave poll (producers 2ks,2ks+1) + 16B fill ----
        if (tt > 0) {
            const int* my_tags = tags + (g * 8 + 2 * ks) * 2;   // 4 contiguous ints
            int4 tv; int it = 0;
            for (;;) {
                asm volatile("global_load_dwordx4 %0, %1, off sc0 sc1\n\ts_waitcnt vmcnt(0)"
                             : "=&v"(tv) : "v"(my_tags) : "memory");
                if (tv.x >= tt && tv.y >= tt && tv.z >= tt && tv.w >= tt) break;
                if (++it > 2) __builtin_amdgcn_s_sleep(2);
                if (it > (1 << 22)) break;   // failsafe (never hit when resident)
            }
            const float* hs = h2 + ((size_t)(g * 2 + par)) * 1024 + (size_t)(ks * 64 + lane) * 4;
            float4 a0;
            asm volatile("global_load_dwordx4 %0, %1, off sc0 sc1\n\ts_waitcnt vmcnt(0)"
                         : "=&v"(a0) : "v"(hs) : "memory");
            __builtin_amdgcn_sched_barrier(0);
            const int u = ks * 64 + lane;   // wave-private column slice
            h_lds[0][u] = a0.x; h_lds[1][u] = a0.y; h_lds[2][u] = a0.z; h_lds[3][u] = a0.w;
        }

        // ---- 4. hh dot: whh(regs) . h_lds (same wave wrote this slice) ----
        #pragma unroll
        for (int m = 0; m < 16; ++m) {
            float4 hv[4];
            #pragma unroll
            for (int u = 0; u < 4; ++u)
                hv[u] = *reinterpret_cast<const float4*>(&h_lds[u][ks * 64 + 4 * m]);
            #pragma unroll
            for (int i = 0; i < 2; ++i) {
                const float4 wv = whh[i][m];
                #pragma unroll
                for (int u = 0; u < 4; ++u)
                    acc[i][u] += wv.x * hv[u].x + wv.y * hv[u].y + wv.z * hv[u].z + wv.w * hv[u].w;
            }
        }

        // ---- 5. write K-partials (parity-buffered) ----
        #pragma unroll
        for (int i = 0; i < 2; ++i)
            #pragma unroll
            for (int u = 0; u < 4; ++u)
                parts[par][ks][lane + 64 * i][u] = acc[i][u];
        __syncthreads();   // SYNC_B: parts[par] ready, emb_lds[par^1] ready

        // ---- 6. pointwise on tid<128: unit u0+(tid>>2), batch b0+(tid&3) ----
        float hval = 0.f;
        if (tid < 128) {
            const int bb = tid & 3;
            const int ul = tid >> 2;
            float gv[4];
            #pragma unroll
            for (int q = 0; q < 4; ++q) {
                const int r = q * 32 + ul;
                gv[q] = parts[par][0][r][bb] + parts[par][1][r][bb]
                      + parts[par][2][r][bb] + parts[par][3][r][bb] + bias_lds[r];
            }
            creg = sigmoidf_(gv[1]) * creg + sigmoidf_(gv[0]) * tanhf(gv[2]);
            hval = sigmoidf_(gv[3]) * tanhf(creg);
            // coalesced: consecutive lanes -> consecutive addresses
            float* dst = h2 + ((size_t)(g * 2 + (par ^ 1))) * 1024 + (size_t)(u0 + ul) * 4 + bb;
            asm volatile("global_store_dword %0, %1, off sc0 sc1"
                         :: "v"(dst), "v"(hval) : "memory");
        }
        // per-wave release: own wave's h stores drained -> publish wave tag
        asm volatile("s_waitcnt vmcnt(0)" ::: "memory");
        if ((tid & 63) == 0 && tid < 128) {
            int val = tt + 1;
            int* rel = tags + (g * 8 + ug) * 2 + (tid >> 6);
            asm volatile("global_store_dword %0, %1, off sc0 sc1"
                         :: "v"(rel), "v"(val) : "memory");
        }
        // h_hist store off the critical path (plain cached store)
        if (tid < 128) {
            const int bb = tid & 3;
            const int ul = tid >> 2;
            const int t_eff = d ? (Lv - 1 - tt) : tt;
            h_hist[((size_t)(b0 + bb) * Lv + t_eff) * 512 + d * 256 + u0 + ul] = hval;
        }
    }
}

// emissions: em[l][b][j] = dot(h_hist[b][l][:512], Wout[j]) + bout[j]
__global__ __launch_bounds__(256) void emis_kernel(
    const float* __restrict__ h_hist, const float* __restrict__ Wout,
    const float* __restrict__ bout, float* __restrict__ em)
{
    const int l  = blockIdx.x >> 2;
    const int bg = blockIdx.x & 3;
    const int tid = threadIdx.x;
    __shared__ float w_lds[9][516];
    __shared__ float h_ldsx[16][512];

    for (int i = tid; i < 9 * 512; i += 256) w_lds[i >> 9][i & 511] = Wout[i];
    for (int i = tid; i < 16 * 128; i += 256) {
        const int bb = i >> 7; const int k = (i & 127) * 4;
        *reinterpret_cast<float4*>(&h_ldsx[bb][k]) =
            *reinterpret_cast<const float4*>(&h_hist[((size_t)(bg * 16 + bb) * 512 + l) * 512 + k]);
    }
    __syncthreads();

    const int bb = tid >> 4;
    const int j = tid & 15;
    if (j < 9) {
        float acc = bout[j];
        #pragma unroll 4
        for (int k = 0; k < 512; k += 4) {
            float4 hv = *reinterpret_cast<const float4*>(&h_ldsx[bb][k]);
            float4 wv = *reinterpret_cast<const float4*>(&w_lds[j][k]);
            acc += hv.x * wv.x + hv.y * wv.y + hv.z * wv.z + hv.w * wv.w;
        }
        em[((size_t)l * 64 + bg * 16 + bb) * 9 + j] = acc;
    }
}

__global__ __launch_bounds__(576) void viterbi_fwd(
    const float* __restrict__ em, const float* __restrict__ start,
    const float* __restrict__ trans, const float* __restrict__ endt,
    unsigned char* __restrict__ hist, int* __restrict__ last_tag,
    float* __restrict__ out_best)
{
    const int tid = threadIdx.x;
    const int b = tid / 9;
    const int j = tid - b * 9;
    __shared__ float sc[2][64][9];
    float t9[9];
    #pragma unroll
    for (int i = 0; i < 9; ++i) t9[i] = trans[i * 9 + j];

    sc[0][b][j] = start[j] + em[tid];
    float emv = em[(64 + b) * 9 + j];
    __syncthreads();
    for (int t = 1; t < 512; ++t) {
        float em_nxt = (t < 511) ? em[((t + 1) * 64 + b) * 9 + j] : 0.f;
        const int cur = t & 1, prv = cur ^ 1;
        float best = -1e30f; int arg = 0;
        #pragma unroll
        for (int i = 0; i < 9; ++i) {
            float v = sc[prv][b][i] + t9[i];
            if (v > best) { best = v; arg = i; }
        }
        best += emv;
        sc[cur][b][j] = best;
        hist[((size_t)b * 512 + t) * 9 + j] = (unsigned char)arg;
        __syncthreads();
        emv = em_nxt;
    }
    sc[1][b][j] += endt[j];
    __syncthreads();
    if (j == 0) {
        float best = -1e30f; int arg = 0;
        #pragma unroll
        for (int i = 0; i < 9; ++i) {
            float v = sc[1][b][i];
            if (v > best) { best = v; arg = i; }
        }
        out_best[b] = best;
        last_tag[b] = arg;
    }
}

__global__ __launch_bounds__(256) void backtrack(
    const unsigned char* __restrict__ hist, const int* __restrict__ last_tag,
    float* __restrict__ out_tags)
{
    const int b = blockIdx.x;
    const int tid = threadIdx.x;
    __shared__ __align__(16) unsigned char hl[512 * 9];
    const uint4* src = reinterpret_cast<const uint4*>(hist + (size_t)b * 512 * 9);
    uint4* dst = reinterpret_cast<uint4*>(hl);
    for (int i = tid; i < 512 * 9 / 16; i += 256) dst[i] = src[i];
    __syncthreads();
    if (tid == 0) {
        int tag = last_tag[b];
        out_tags[b * 512 + 511] = (float)tag;
        for (int t = 511; t >= 1; --t) {
            tag = hl[t * 9 + tag];
            out_tags[b * 512 + t - 1] = (float)tag;
        }
    }
}

extern "C" void kernel_launch(void* const* d_in, const int* in_sizes, int n_in,
                              void* d_out, int out_size, void* d_ws, size_t ws_size,
                              hipStream_t stream)
{
    const int*   x     = (const int*)d_in[0];
    const float* embed = (const float*)d_in[1];
    const float* Wih_f = (const float*)d_in[2];
    const float* Whh_f = (const float*)d_in[3];
    const float* bf    = (const float*)d_in[4];
    const float* Wih_b = (const float*)d_in[5];
    const float* Whh_b = (const float*)d_in[6];
    const float* bb    = (const float*)d_in[7];
    const float* Wout  = (const float*)d_in[8];
    const float* bout  = (const float*)d_in[9];
    const float* start = (const float*)d_in[10];
    const float* trans = (const float*)d_in[11];
    const float* endt  = (const float*)d_in[12];

    char* ws = (char*)d_ws;
    float* h_hist = (float*)ws;                              // 67,108,864 @ 0
    float* h2     = (float*)(ws + 67108864ULL);              // 262,144
    int*   tags   = (int*)(ws + 67371008ULL);                // 2,048
    float* em     = (float*)(ws + 67373056ULL);              // 1,179,648
    int*   last_tag = (int*)(ws + 68552704ULL);              // 256
    unsigned char* hist = (unsigned char*)(ws + 68552960ULL); // 294,912

    float* out = (float*)d_out;   // [64*512 tags][64 best], all f32

    hipMemsetAsync(tags, 0, 2048, stream);   // tags = 0 each call

    lstm_persist<<<256, 256, 56000, stream>>>(x, embed, Wih_f, Whh_f, bf,
                                              Wih_b, Whh_b, bb,
                                              h2, tags, h_hist);
    emis_kernel<<<2048, 256, 0, stream>>>(h_hist, Wout, bout, em);
    viterbi_fwd<<<1, 576, 0, stream>>>(em, start, trans, endt, hist, last_tag, out + 64 * 512);
    backtrack<<<64, 256, 0, stream>>>(hist, last_tag, out);
}